// Round 14
// baseline (1034.847 us; speedup 1.0000x reference)
//
#include <hip/hip_runtime.h>
#include <hip/hip_cooperative_groups.h>

typedef unsigned short u16;
typedef unsigned int   u32;

typedef short short8 __attribute__((ext_vector_type(8)));
typedef float floatx4 __attribute__((ext_vector_type(4)));

#define CDIM 128
#define K_NEG_LOG2E -1.4426950408889634f
#define CNT_SCALE 16777216.0   // 2^24: packs (sum, count) into one f64

// LDS weight tile (fallback path only): 128 rows x 136 u16.
#define WLDS_STRIDE 136
#define PACK_BLOCKS 512

__device__ __forceinline__ float bf2f_lo(u32 h) {
    union { u32 u; float f; } v; v.u = h << 16; return v.f;
}
__device__ __forceinline__ float bf2f_hi(u32 h) {
    union { u32 u; float f; } v; v.u = h & 0xffff0000u; return v.f;
}
__device__ __forceinline__ u16 f2bf(float f) {
    union { float f; u32 u; } v; v.f = f;
    u32 u = v.u;
    return (u16)((u + 0x7FFFu + ((u >> 16) & 1u)) >> 16);  // RNE
}
__device__ __forceinline__ float sig_std(float x) {
    return __builtin_amdgcn_rcpf(1.0f + __builtin_amdgcn_exp2f(x * K_NEG_LOG2E));
}

// ---------------- proj tile, W read from GLOBAL f32 (no LDS) ----------------
// In-register W conversion (pre-scaled by K_NEG_LOG2E). W is 128 KB and
// L2-resident; per-wave conversion cost ~3 us chip-wide. Zero LDS keeps the
// mega kernel at 8 blocks/CU co-residency for the edge phase.
__device__ __forceinline__ void proj_tile16_greg(
    const float* __restrict__ X, const float* __restrict__ W,
    const float* __restrict__ bias, u16* __restrict__ out,
    int nrows, int ostride, int ooff, int row0, int lane)
{
    const int m = lane & 15;   // A-row / B-col / D-col
    const int g = lane >> 4;   // k-quad

    short8 a[4];
    {
        int arow = row0 + m;
        if (arow >= nrows) arow = nrows - 1;   // clamp; stores masked below
        const float* xrow = X + (size_t)arow * CDIM;
#pragma unroll
        for (int s = 0; s < 4; ++s) {
            float4 f0 = *(const float4*)(xrow + s * 32 + g * 8);
            float4 f1 = *(const float4*)(xrow + s * 32 + g * 8 + 4);
            a[s][0] = (short)f2bf(f0.x); a[s][1] = (short)f2bf(f0.y);
            a[s][2] = (short)f2bf(f0.z); a[s][3] = (short)f2bf(f0.w);
            a[s][4] = (short)f2bf(f1.x); a[s][5] = (short)f2bf(f1.y);
            a[s][6] = (short)f2bf(f1.z); a[s][7] = (short)f2bf(f1.w);
        }
    }

#pragma unroll
    for (int ct = 0; ct < 8; ++ct) {
        const float* wrow = W + (size_t)(ct * 16 + m) * CDIM;
        floatx4 acc = {0.f, 0.f, 0.f, 0.f};
#pragma unroll
        for (int s = 0; s < 4; ++s) {
            float4 w0 = *(const float4*)(wrow + s * 32 + g * 8);
            float4 w1 = *(const float4*)(wrow + s * 32 + g * 8 + 4);
            short8 b;
            b[0] = (short)f2bf(w0.x * K_NEG_LOG2E);
            b[1] = (short)f2bf(w0.y * K_NEG_LOG2E);
            b[2] = (short)f2bf(w0.z * K_NEG_LOG2E);
            b[3] = (short)f2bf(w0.w * K_NEG_LOG2E);
            b[4] = (short)f2bf(w1.x * K_NEG_LOG2E);
            b[5] = (short)f2bf(w1.y * K_NEG_LOG2E);
            b[6] = (short)f2bf(w1.z * K_NEG_LOG2E);
            b[7] = (short)f2bf(w1.w * K_NEG_LOG2E);
            acc = __builtin_amdgcn_mfma_f32_16x16x32_bf16(a[s], b, acc, 0, 0, 0);
        }
        const int col = ct * 16 + m;           // D: col = lane&15
        const float badd = bias ? bias[col] * K_NEG_LOG2E : 0.f;
#pragma unroll
        for (int i = 0; i < 4; ++i) {
            int r = row0 + g * 4 + i;          // D: row = (lane>>4)*4 + reg
            if (r < nrows)
                out[(size_t)r * ostride + ooff + col] =
                    f2bf(__builtin_amdgcn_exp2f(acc[i] + badd));
        }
    }
}

// ======================= MEGA KERNEL (cooperative) ==========================
// Phase A: pack/zero + all projections (grid-stride over roles, no LDS).
// grid.sync -> Phase B: edge (R8 structure: depth-2 stu/item, depth-3 idx).
// grid.sync -> Phase C: final sigmoid-of-mean.
// Collapses 3 launches into 1 — targets the ~50-100 us of per-iteration
// time not visible in any kernel dispatch (launch/tail/gap overhead).
__global__ __launch_bounds__(256, 8) void mega_kernel(
    const float* __restrict__ stu_x, const float* __restrict__ item_x,
    const float* __restrict__ conc_x,
    const float* __restrict__ Wstu, const float* __restrict__ Witem,
    const float* __restrict__ b_stu, const float* __restrict__ b_item,
    const float* __restrict__ w_pred, const float* __restrict__ b_pred,
    u16* __restrict__ stu_p, u16* __restrict__ item_p, u16* __restrict__ conc_cat,
    double* __restrict__ sc, float* __restrict__ out,
    const int* __restrict__ stu_track, const int* __restrict__ item_index,
    const int* __restrict__ conc_index, const int* __restrict__ mean_index,
    int4* __restrict__ idx4, int E, int NS, int NI, int NC, int M, int nZero4)
{
    const int PB0 = (NS + 63) / 64, PB1 = (NI + 63) / 64, PB2 = (NC + 63) / 64;
    const int PBtot = PB0 + PB1 + 2 * PB2;
    const int ROLES = PACK_BLOCKS + PBtot;

    // ---------------- Phase A: pack/zero + projections ----------------
    for (int role = blockIdx.x; role < ROLES; role += gridDim.x) {
        if (role < PACK_BLOCKS) {
            const int tid0 = role * 256 + threadIdx.x;
            const int stride = PACK_BLOCKS * 256;
            const float4 z = {0.f, 0.f, 0.f, 0.f};
            for (int i = tid0; i < nZero4; i += stride) ((float4*)sc)[i] = z;
            for (int e = tid0; e < E; e += stride) {
                int4 t;
                t.x = stu_track[e]  << 8;   // 256 B rows
                t.y = item_index[e] << 8;   // 256 B rows
                t.z = conc_index[e] << 9;   // 512 B rows (cat)
                t.w = mean_index[e] << 3;   // f64 slots
                idx4[e] = t;
            }
        } else {
            int b = role - PACK_BLOCKS;
            const float* X; const float* Wsel; const float* bias;
            u16* outp; int nrows, ostride, ooff, base;
            if (b < PB0)      { X = stu_x;  Wsel = Wstu;  bias = nullptr; outp = stu_p;
                                nrows = NS; ostride = 128; ooff = 0;   base = b * 64; }
            else if ((b -= PB0) < PB1)
                              { X = item_x; Wsel = Witem; bias = nullptr; outp = item_p;
                                nrows = NI; ostride = 128; ooff = 0;   base = b * 64; }
            else if ((b -= PB1) < PB2)
                              { X = conc_x; Wsel = Wstu;  bias = b_stu;  outp = conc_cat;
                                nrows = NC; ostride = 256; ooff = 0;   base = b * 64; }
            else              { b -= PB2;
                                X = conc_x; Wsel = Witem; bias = b_item; outp = conc_cat;
                                nrows = NC; ostride = 256; ooff = 128; base = b * 64; }
            const int lane = threadIdx.x & 63;
            const int row0 = base + (threadIdx.x >> 6) * 16;
            if (row0 < nrows)
                proj_tile16_greg(X, Wsel, bias, outp, nrows, ostride, ooff, row0, lane);
        }
    }

    __threadfence();                       // device-scope: cross-XCD visibility
    cooperative_groups::this_grid().sync();

    // ---------------- Phase B: edge (R8 proven structure) ----------------
    {
        const int lane = threadIdx.x & 63;
        const int sub  = lane & 15;      // position within edge
        const int g    = lane >> 4;      // edge within quad
        const int waveId = (int)((blockIdx.x * blockDim.x + threadIdx.x) >> 6);
        const int S      = (int)((gridDim.x * blockDim.x) >> 6);

        const float4 wA = ((const float4*)w_pred)[sub * 2];
        const float4 wB = ((const float4*)w_pred)[sub * 2 + 1];
        float2 w2[4];
        w2[0] = make_float2(wA.x, wA.y); w2[1] = make_float2(wA.z, wA.w);
        w2[2] = make_float2(wB.x, wB.y); w2[3] = make_float2(wB.z, wB.w);
        const u32 lane_off = (u32)sub * 16;

        const int nQuads = (E + 3) >> 2;
        int q = waveId;
        if (q < nQuads) {
            auto ldidx = [&](int qq) -> int4 {
                int e = qq * 4 + g;
                e = (e < E) ? e : (E - 1);
                return idx4[e];
            };
            auto compute = [&](const uint4& sv, const uint4& iv,
                               const uint4& ca, const uint4& cb,
                               u32 mw, int qq) {
                const u32 su[4] = {sv.x, sv.y, sv.z, sv.w};
                const u32 iu[4] = {iv.x, iv.y, iv.z, iv.w};
                const u32 au[4] = {ca.x, ca.y, ca.z, ca.w};
                const u32 bu[4] = {cb.x, cb.y, cb.z, cb.w};
                const float2 one = make_float2(1.f, 1.f);
                float2 vacc = make_float2(0.f, 0.f);
#pragma unroll
                for (int j = 0; j < 4; ++j) {
                    float2 A  = make_float2(bf2f_lo(au[j]), bf2f_hi(au[j]));
                    float2 Sx = make_float2(bf2f_lo(su[j]), bf2f_hi(su[j]));
                    float2 B  = make_float2(bf2f_lo(bu[j]), bf2f_hi(bu[j]));
                    float2 Ix = make_float2(bf2f_lo(iu[j]), bf2f_hi(iu[j]));
                    float2 ea = A * Sx;
                    float2 eb = B * Ix;
                    float2 den = (ea + one) * (eb + one);
                    float2 num = eb - ea;
                    float2 rd = make_float2(__builtin_amdgcn_rcpf(den.x),
                                            __builtin_amdgcn_rcpf(den.y));
                    vacc += (num * rd) * w2[j];
                }
                float v = vacc.x + vacc.y;
                v += __shfl_xor(v, 1, 64);
                v += __shfl_xor(v, 2, 64);
                v += __shfl_xor(v, 4, 64);
                v += __shfl_xor(v, 8, 64);
                if (sub == 0 && (qq * 4 + g) < E)
                    atomicAdd((double*)((char*)sc + mw), (double)v + CNT_SCALE);
            };

#define GATH_S(I_, sv_, iv_) { \
        sv_ = *(const uint4*)((const char*)stu_p  + ((u32)(I_).x + lane_off)); \
        iv_ = *(const uint4*)((const char*)item_p + ((u32)(I_).y + lane_off)); }
#define GATH_C(I_, ca_, cb_) { \
        const char* cp_ = (const char*)conc_cat + ((u32)(I_).z + lane_off); \
        ca_ = *(const uint4*)cp_; cb_ = *(const uint4*)(cp_ + 256); }
#define STEP(SC, CC, IC, ICN1, ICN2, SF, CF) { \
        const u32 mw = (u32)IC.w; \
        IC = ldidx(q + 3 * S); \
        __builtin_amdgcn_sched_barrier(0); \
        GATH_C(ICN1, CF##a, CF##b); \
        GATH_S(ICN2, SF##s, SF##i); \
        __builtin_amdgcn_sched_barrier(0); \
        compute(SC##s, SC##i, CC##a, CC##b, mw, q); \
        q += S; \
        if (q >= nQuads) break; }

            int4 i0 = ldidx(q), i1 = ldidx(q + S), i2 = ldidx(q + 2 * S);
            uint4 s0s, s0i, s1s, s1i, s2s, s2i, c0a, c0b, c1a, c1b;
            GATH_C(i0, c0a, c0b);
            GATH_S(i0, s0s, s0i);
            GATH_S(i1, s1s, s1i);

            for (;;) {
                STEP(s0, c0, i0, i1, i2, s2, c1)
                STEP(s1, c1, i1, i2, i0, s0, c0)
                STEP(s2, c0, i2, i0, i1, s1, c1)
                STEP(s0, c1, i0, i1, i2, s2, c0)
                STEP(s1, c0, i1, i2, i0, s0, c1)
                STEP(s2, c1, i2, i0, i1, s1, c0)
            }
#undef STEP
#undef GATH_S
#undef GATH_C
        }
    }

    __threadfence();
    cooperative_groups::this_grid().sync();

    // ---------------- Phase C: final ----------------
    for (int i = blockIdx.x * 256 + threadIdx.x; i < M; i += gridDim.x * 256) {
        const double acc = sc[i];
        const double cnt = rint(acc * (1.0 / CNT_SCALE));
        const double sum = acc - cnt * CNT_SCALE;
        const float mean = (float)(sum / fmax(cnt, 1.0));
        out[i] = sig_std(mean + b_pred[0]);
    }
}

// ===================== FALLBACK: proven R13 3-kernel path ====================
__device__ __forceinline__ void proj_tile16_lds(
    const float* __restrict__ X, const u16* __restrict__ wlds,
    const float* __restrict__ bias, u16* __restrict__ out,
    int nrows, int ostride, int ooff, int row0, int lane)
{
    const int m = lane & 15;
    const int g = lane >> 4;
    short8 a[4];
    {
        int arow = row0 + m;
        if (arow >= nrows) arow = nrows - 1;
        const float* xrow = X + (size_t)arow * CDIM;
#pragma unroll
        for (int s = 0; s < 4; ++s) {
            float4 f0 = *(const float4*)(xrow + s * 32 + g * 8);
            float4 f1 = *(const float4*)(xrow + s * 32 + g * 8 + 4);
            a[s][0] = (short)f2bf(f0.x); a[s][1] = (short)f2bf(f0.y);
            a[s][2] = (short)f2bf(f0.z); a[s][3] = (short)f2bf(f0.w);
            a[s][4] = (short)f2bf(f1.x); a[s][5] = (short)f2bf(f1.y);
            a[s][6] = (short)f2bf(f1.z); a[s][7] = (short)f2bf(f1.w);
        }
    }
#pragma unroll
    for (int ct = 0; ct < 8; ++ct) {
        const u16* wrow = wlds + (size_t)(ct * 16 + m) * WLDS_STRIDE;
        floatx4 acc = {0.f, 0.f, 0.f, 0.f};
#pragma unroll
        for (int s = 0; s < 4; ++s) {
            short8 b = *(const short8*)(wrow + s * 32 + g * 8);
            acc = __builtin_amdgcn_mfma_f32_16x16x32_bf16(a[s], b, acc, 0, 0, 0);
        }
        const int col = ct * 16 + m;
        const float badd = bias ? bias[col] * K_NEG_LOG2E : 0.f;
#pragma unroll
        for (int i = 0; i < 4; ++i) {
            int r = row0 + g * 4 + i;
            if (r < nrows)
                out[(size_t)r * ostride + ooff + col] =
                    f2bf(__builtin_amdgcn_exp2f(acc[i] + badd));
        }
    }
}

__global__ __launch_bounds__(256) void fused_prep_proj(
    const float* __restrict__ stu_x, const float* __restrict__ item_x,
    const float* __restrict__ conc_x,
    const float* __restrict__ Wstu, const float* __restrict__ Witem,
    const float* __restrict__ b_stu, const float* __restrict__ b_item,
    u16* __restrict__ stu_p, u16* __restrict__ item_p, u16* __restrict__ conc_cat,
    float4* __restrict__ zero4, int nZero4,
    const int* __restrict__ stu_track, const int* __restrict__ item_index,
    const int* __restrict__ conc_index, const int* __restrict__ mean_index,
    int4* __restrict__ idx4, int E,
    int NS, int NI, int NC)
{
    __shared__ u16 wlds[128 * WLDS_STRIDE];
    const int PB0 = (NS + 63) / 64, PB1 = (NI + 63) / 64, PB2 = (NC + 63) / 64;
    const int PBtot = PB0 + PB1 + 2 * PB2;
    int b = blockIdx.x;
    if (b < PACK_BLOCKS) {
        const int tid = b * 256 + threadIdx.x;
        const int stride = PACK_BLOCKS * 256;
        const float4 z = {0.f, 0.f, 0.f, 0.f};
        for (int i = tid; i < nZero4; i += stride) zero4[i] = z;
        for (int e = tid; e < E; e += stride) {
            int4 t;
            t.x = stu_track[e]  << 8;
            t.y = item_index[e] << 8;
            t.z = conc_index[e] << 9;
            t.w = mean_index[e] << 3;
            idx4[e] = t;
        }
        return;
    }
    b -= PACK_BLOCKS;
    if (b >= PBtot) return;
    const float* X; const float* Wsel; const float* bias;
    u16* out; int nrows, ostride, ooff, base;
    if (b < PB0)      { X = stu_x;  Wsel = Wstu;  bias = nullptr; out = stu_p;
                        nrows = NS; ostride = 128; ooff = 0;   base = b * 64; }
    else if ((b -= PB0) < PB1)
                      { X = item_x; Wsel = Witem; bias = nullptr; out = item_p;
                        nrows = NI; ostride = 128; ooff = 0;   base = b * 64; }
    else if ((b -= PB1) < PB2)
                      { X = conc_x; Wsel = Wstu;  bias = b_stu;  out = conc_cat;
                        nrows = NC; ostride = 256; ooff = 0;   base = b * 64; }
    else              { b -= PB2;
                        X = conc_x; Wsel = Witem; bias = b_item; out = conc_cat;
                        nrows = NC; ostride = 256; ooff = 128; base = b * 64; }
    {
        const int t   = threadIdx.x;
        const int col = t >> 1;
        const int k0  = (t & 1) * 64;
        const float4* src = (const float4*)(Wsel + col * 128 + k0);
        u32* dst = (u32*)(wlds + col * WLDS_STRIDE + k0);
#pragma unroll
        for (int i = 0; i < 16; ++i) {
            float4 f = src[i];
            dst[2 * i]     = (u32)f2bf(f.x * K_NEG_LOG2E) |
                             ((u32)f2bf(f.y * K_NEG_LOG2E) << 16);
            dst[2 * i + 1] = (u32)f2bf(f.z * K_NEG_LOG2E) |
                             ((u32)f2bf(f.w * K_NEG_LOG2E) << 16);
        }
    }
    __syncthreads();
    const int lane = threadIdx.x & 63;
    const int row0 = base + (threadIdx.x >> 6) * 16;
    if (row0 < nrows)
        proj_tile16_lds(X, wlds, bias, out, nrows, ostride, ooff, row0, lane);
}

__global__ __launch_bounds__(256) void edge_kernel(
    const u16* __restrict__ stu_p, const u16* __restrict__ item_p,
    const u16* __restrict__ conc_cat,
    const int4* __restrict__ idx4,
    const float* __restrict__ w_pred,
    double* __restrict__ sc, int E)
{
    const int lane = threadIdx.x & 63;
    const int sub  = lane & 15;
    const int g    = lane >> 4;
    const int waveId = (int)((blockIdx.x * blockDim.x + threadIdx.x) >> 6);
    const int S      = (int)((gridDim.x * blockDim.x) >> 6);

    const float4 wA = ((const float4*)w_pred)[sub * 2];
    const float4 wB = ((const float4*)w_pred)[sub * 2 + 1];
    float2 w2[4];
    w2[0] = make_float2(wA.x, wA.y); w2[1] = make_float2(wA.z, wA.w);
    w2[2] = make_float2(wB.x, wB.y); w2[3] = make_float2(wB.z, wB.w);
    const u32 lane_off = (u32)sub * 16;

    const int nQuads = (E + 3) >> 2;
    int q = waveId;
    if (q >= nQuads) return;

    auto ldidx = [&](int qq) -> int4 {
        int e = qq * 4 + g;
        e = (e < E) ? e : (E - 1);
        return idx4[e];
    };
    auto compute = [&](const uint4& sv, const uint4& iv,
                       const uint4& ca, const uint4& cb,
                       u32 mw, int qq) {
        const u32 su[4] = {sv.x, sv.y, sv.z, sv.w};
        const u32 iu[4] = {iv.x, iv.y, iv.z, iv.w};
        const u32 au[4] = {ca.x, ca.y, ca.z, ca.w};
        const u32 bu[4] = {cb.x, cb.y, cb.z, cb.w};
        const float2 one = make_float2(1.f, 1.f);
        float2 vacc = make_float2(0.f, 0.f);
#pragma unroll
        for (int j = 0; j < 4; ++j) {
            float2 A  = make_float2(bf2f_lo(au[j]), bf2f_hi(au[j]));
            float2 Sx = make_float2(bf2f_lo(su[j]), bf2f_hi(su[j]));
            float2 B  = make_float2(bf2f_lo(bu[j]), bf2f_hi(bu[j]));
            float2 Ix = make_float2(bf2f_lo(iu[j]), bf2f_hi(iu[j]));
            float2 ea = A * Sx;
            float2 eb = B * Ix;
            float2 den = (ea + one) * (eb + one);
            float2 num = eb - ea;
            float2 rd = make_float2(__builtin_amdgcn_rcpf(den.x),
                                    __builtin_amdgcn_rcpf(den.y));
            vacc += (num * rd) * w2[j];
        }
        float v = vacc.x + vacc.y;
        v += __shfl_xor(v, 1, 64);
        v += __shfl_xor(v, 2, 64);
        v += __shfl_xor(v, 4, 64);
        v += __shfl_xor(v, 8, 64);
        if (sub == 0 && (qq * 4 + g) < E)
            atomicAdd((double*)((char*)sc + mw), (double)v + CNT_SCALE);
    };

#define GATH_S(I_, sv_, iv_) { \
        sv_ = *(const uint4*)((const char*)stu_p  + ((u32)(I_).x + lane_off)); \
        iv_ = *(const uint4*)((const char*)item_p + ((u32)(I_).y + lane_off)); }
#define GATH_C(I_, ca_, cb_) { \
        const char* cp_ = (const char*)conc_cat + ((u32)(I_).z + lane_off); \
        ca_ = *(const uint4*)cp_; cb_ = *(const uint4*)(cp_ + 256); }
#define STEP(SC, CC, IC, ICN1, ICN2, SF, CF) { \
        const u32 mw = (u32)IC.w; \
        IC = ldidx(q + 3 * S); \
        __builtin_amdgcn_sched_barrier(0); \
        GATH_C(ICN1, CF##a, CF##b); \
        GATH_S(ICN2, SF##s, SF##i); \
        __builtin_amdgcn_sched_barrier(0); \
        compute(SC##s, SC##i, CC##a, CC##b, mw, q); \
        q += S; \
        if (q >= nQuads) break; }

    int4 i0 = ldidx(q), i1 = ldidx(q + S), i2 = ldidx(q + 2 * S);
    uint4 s0s, s0i, s1s, s1i, s2s, s2i, c0a, c0b, c1a, c1b;
    GATH_C(i0, c0a, c0b);
    GATH_S(i0, s0s, s0i);
    GATH_S(i1, s1s, s1i);

    for (;;) {
        STEP(s0, c0, i0, i1, i2, s2, c1)
        STEP(s1, c1, i1, i2, i0, s0, c0)
        STEP(s2, c0, i2, i0, i1, s1, c1)
        STEP(s0, c1, i0, i1, i2, s2, c0)
        STEP(s1, c0, i1, i2, i0, s0, c1)
        STEP(s2, c1, i2, i0, i1, s1, c0)
    }
#undef STEP
#undef GATH_S
#undef GATH_C
}

__global__ __launch_bounds__(256) void final_kernel(
    const double* __restrict__ sc,
    const float* __restrict__ b_pred, float* __restrict__ out, int M)
{
    const int i = blockIdx.x * blockDim.x + threadIdx.x;
    if (i < M) {
        const double acc = sc[i];
        const double cnt = rint(acc * (1.0 / CNT_SCALE));
        const double sum = acc - cnt * CNT_SCALE;
        const float mean = (float)(sum / fmax(cnt, 1.0));
        out[i] = sig_std(mean + b_pred[0]);
    }
}

extern "C" void kernel_launch(void* const* d_in, const int* in_sizes, int n_in,
                              void* d_out, int out_size, void* d_ws, size_t ws_size,
                              hipStream_t stream) {
    const float* stu_x    = (const float*)d_in[0];
    const float* item_x   = (const float*)d_in[1];
    const float* conc_x   = (const float*)d_in[2];
    const float* W_stu    = (const float*)d_in[3];
    const float* b_stu    = (const float*)d_in[4];
    const float* W_item   = (const float*)d_in[5];
    const float* b_item   = (const float*)d_in[6];
    const float* W_pred   = (const float*)d_in[7];
    const float* b_pred   = (const float*)d_in[8];
    const int* stu_track  = (const int*)d_in[9];
    const int* item_index = (const int*)d_in[10];
    const int* conc_index = (const int*)d_in[11];
    const int* mean_index = (const int*)d_in[12];

    int NS = in_sizes[0] / CDIM;
    int NI = in_sizes[1] / CDIM;
    int NC = in_sizes[2] / CDIM;
    int E  = in_sizes[9];
    int M  = out_size;

    // workspace layout (all pieces 16B-aligned)
    double* sc     = (double*)d_ws;              // [M] packed (sum + cnt*2^24)
    u16* stu_p     = (u16*)(sc + M);
    u16* item_p    = stu_p  + (size_t)NS * CDIM;
    u16* conc_cat  = item_p + (size_t)NI * CDIM; // [NC][256]: exp2 stu | item side
    int4* idx4     = (int4*)(conc_cat + (size_t)NC * 256);

    int nZero4 = (int)(((size_t)M * sizeof(double)) / 16);
    const int PB0 = (NS + 63) / 64, PB1 = (NI + 63) / 64, PB2 = (NC + 63) / 64;
    const int PBtot = PB0 + PB1 + 2 * PB2;

    // ---- try single cooperative launch ----
    int dev = 0;
    (void)hipGetDevice(&dev);
    int coop = 0, numCU = 0, bpc = 0;
    (void)hipDeviceGetAttribute(&coop, hipDeviceAttributeCooperativeLaunch, dev);
    (void)hipDeviceGetAttribute(&numCU, hipDeviceAttributeMultiprocessorCount, dev);
    (void)hipOccupancyMaxActiveBlocksPerMultiprocessor(&bpc, mega_kernel, 256, 0);
    long long Gll = (long long)bpc * (long long)numCU;
    int G = (Gll > 2048) ? 2048 : (int)Gll;

    if (coop && G >= 256) {
        float* outp = (float*)d_out;
        void* args[] = {
            (void*)&stu_x, (void*)&item_x, (void*)&conc_x,
            (void*)&W_stu, (void*)&W_item,
            (void*)&b_stu, (void*)&b_item,
            (void*)&W_pred, (void*)&b_pred,
            (void*)&stu_p, (void*)&item_p, (void*)&conc_cat,
            (void*)&sc, (void*)&outp,
            (void*)&stu_track, (void*)&item_index,
            (void*)&conc_index, (void*)&mean_index,
            (void*)&idx4, (void*)&E, (void*)&NS, (void*)&NI, (void*)&NC,
            (void*)&M, (void*)&nZero4
        };
        hipError_t err = hipLaunchCooperativeKernel(
            (const void*)mega_kernel, dim3(G), dim3(256), args, 0, stream);
        if (err == hipSuccess) return;
    }

    // ---- fallback: proven R13 3-kernel path (190.4 us) ----
    fused_prep_proj<<<PACK_BLOCKS + PBtot, 256, 0, stream>>>(
        stu_x, item_x, conc_x, W_stu, W_item, b_stu, b_item,
        stu_p, item_p, conc_cat,
        (float4*)sc, nZero4,
        stu_track, item_index, conc_index, mean_index, idx4, E,
        NS, NI, NC);
    edge_kernel<<<4096, 256, 0, stream>>>(stu_p, item_p, conc_cat,
                                          idx4, W_pred, sc, E);
    final_kernel<<<(M + 255) / 256, 256, 0, stream>>>(sc, b_pred, (float*)d_out, M);
}

// Round 15
// 463.995 us; speedup vs baseline: 2.2303x; 2.2303x over previous
//
#include <hip/hip_runtime.h>
#include <hip/hip_cooperative_groups.h>

typedef unsigned short u16;
typedef unsigned int   u32;

typedef short short8 __attribute__((ext_vector_type(8)));
typedef float floatx4 __attribute__((ext_vector_type(4)));

#define CDIM 128
#define K_NEG_LOG2E -1.4426950408889634f
#define CNT_SCALE 16777216.0   // 2^24: packs (sum, count) into one f64

// LDS weight tile: 128 rows x 136 u16 (272 B stride).
#define WLDS_STRIDE 136
#define PACK_BLOCKS 512

__device__ __forceinline__ float bf2f_lo(u32 h) {
    union { u32 u; float f; } v; v.u = h << 16; return v.f;
}
__device__ __forceinline__ float bf2f_hi(u32 h) {
    union { u32 u; float f; } v; v.u = h & 0xffff0000u; return v.f;
}
__device__ __forceinline__ u16 f2bf(float f) {
    union { float f; u32 u; } v; v.f = f;
    u32 u = v.u;
    return (u16)((u + 0x7FFFu + ((u >> 16) & 1u)) >> 16);  // RNE
}
__device__ __forceinline__ float sig_std(float x) {
    return __builtin_amdgcn_rcpf(1.0f + __builtin_amdgcn_exp2f(x * K_NEG_LOG2E));
}

// One wave computes a 16-row tile from the LDS weight tile; stores
// exp2(proj + bias) in bf16. (Proven R13 body.)
__device__ __forceinline__ void proj_tile16_lds(
    const float* __restrict__ X, const u16* __restrict__ wlds,
    const float* __restrict__ bias, u16* __restrict__ out,
    int nrows, int ostride, int ooff, int row0, int lane)
{
    const int m = lane & 15;   // A-row / B-col / D-col
    const int g = lane >> 4;   // k-quad

    short8 a[4];
    {
        int arow = row0 + m;
        if (arow >= nrows) arow = nrows - 1;   // clamp; stores masked below
        const float* xrow = X + (size_t)arow * CDIM;
#pragma unroll
        for (int s = 0; s < 4; ++s) {
            float4 f0 = *(const float4*)(xrow + s * 32 + g * 8);
            float4 f1 = *(const float4*)(xrow + s * 32 + g * 8 + 4);
            a[s][0] = (short)f2bf(f0.x); a[s][1] = (short)f2bf(f0.y);
            a[s][2] = (short)f2bf(f0.z); a[s][3] = (short)f2bf(f0.w);
            a[s][4] = (short)f2bf(f1.x); a[s][5] = (short)f2bf(f1.y);
            a[s][6] = (short)f2bf(f1.z); a[s][7] = (short)f2bf(f1.w);
        }
    }

#pragma unroll
    for (int ct = 0; ct < 8; ++ct) {
        const u16* wrow = wlds + (size_t)(ct * 16 + m) * WLDS_STRIDE;
        floatx4 acc = {0.f, 0.f, 0.f, 0.f};
#pragma unroll
        for (int s = 0; s < 4; ++s) {
            short8 b = *(const short8*)(wrow + s * 32 + g * 8);
            acc = __builtin_amdgcn_mfma_f32_16x16x32_bf16(a[s], b, acc, 0, 0, 0);
        }
        const int col = ct * 16 + m;           // D: col = lane&15
        const float badd = bias ? bias[col] * K_NEG_LOG2E : 0.f;
#pragma unroll
        for (int i = 0; i < 4; ++i) {
            int r = row0 + g * 4 + i;          // D: row = (lane>>4)*4 + reg
            if (r < nrows)
                out[(size_t)r * ostride + ooff + col] =
                    f2bf(__builtin_amdgcn_exp2f(acc[i] + badd));
        }
    }
}

// W staging into LDS + segment select (shared by mega phase A and fallback).
__device__ __forceinline__ void proj_role(
    int b, u16* wlds,
    const float* __restrict__ stu_x, const float* __restrict__ item_x,
    const float* __restrict__ conc_x,
    const float* __restrict__ Wstu, const float* __restrict__ Witem,
    const float* __restrict__ b_stu, const float* __restrict__ b_item,
    u16* __restrict__ stu_p, u16* __restrict__ item_p, u16* __restrict__ conc_cat,
    int NS, int NI, int NC,
    int PB0, int PB1, int PB2)
{
    const float* X; const float* Wsel; const float* bias;
    u16* out; int nrows, ostride, ooff, base;
    if (b < PB0)      { X = stu_x;  Wsel = Wstu;  bias = nullptr; out = stu_p;
                        nrows = NS; ostride = 128; ooff = 0;   base = b * 64; }
    else if ((b -= PB0) < PB1)
                      { X = item_x; Wsel = Witem; bias = nullptr; out = item_p;
                        nrows = NI; ostride = 128; ooff = 0;   base = b * 64; }
    else if ((b -= PB1) < PB2)
                      { X = conc_x; Wsel = Wstu;  bias = b_stu;  out = conc_cat;
                        nrows = NC; ostride = 256; ooff = 0;   base = b * 64; }
    else              { b -= PB2;
                        X = conc_x; Wsel = Witem; bias = b_item; out = conc_cat;
                        nrows = NC; ostride = 256; ooff = 128; base = b * 64; }

    // convert this block's W (f32 -> pre-scaled bf16) into LDS
    {
        const int t   = threadIdx.x;
        const int col = t >> 1;
        const int k0  = (t & 1) * 64;
        const float4* src = (const float4*)(Wsel + col * 128 + k0);
        u32* dst = (u32*)(wlds + col * WLDS_STRIDE + k0);
#pragma unroll
        for (int i = 0; i < 16; ++i) {
            float4 f = src[i];
            dst[2 * i]     = (u32)f2bf(f.x * K_NEG_LOG2E) |
                             ((u32)f2bf(f.y * K_NEG_LOG2E) << 16);
            dst[2 * i + 1] = (u32)f2bf(f.z * K_NEG_LOG2E) |
                             ((u32)f2bf(f.w * K_NEG_LOG2E) << 16);
        }
    }
    __syncthreads();

    const int lane = threadIdx.x & 63;
    const int row0 = base + (threadIdx.x >> 6) * 16;
    if (row0 < nrows)
        proj_tile16_lds(X, wlds, bias, out, nrows, ostride, ooff, row0, lane);
}

// ======================= MEGA KERNEL (cooperative) ==========================
// Phase A: pack/zero + projections (grid-stride roles, LDS-staged W).
// grid.sync -> Phase B: edge (R8 structure). grid.sync -> Phase C: final.
// R13's failure was __launch_bounds__(256,8): the min-occupancy clamp forced
// VGPR=32 -> total spill (1.16GB FETCH / 838MB WRITE scratch, 1498 us).
// Fix: plain launch_bounds; LDS (34.8KB) caps at 4 blocks/CU = 16 waves/CU,
// >= edge's measured steady-state residency (~12 waves/CU at occ 37%).
__global__ __launch_bounds__(256) void mega_kernel(
    const float* __restrict__ stu_x, const float* __restrict__ item_x,
    const float* __restrict__ conc_x,
    const float* __restrict__ Wstu, const float* __restrict__ Witem,
    const float* __restrict__ b_stu, const float* __restrict__ b_item,
    const float* __restrict__ w_pred, const float* __restrict__ b_pred,
    u16* __restrict__ stu_p, u16* __restrict__ item_p, u16* __restrict__ conc_cat,
    double* __restrict__ sc, float* __restrict__ out,
    const int* __restrict__ stu_track, const int* __restrict__ item_index,
    const int* __restrict__ conc_index, const int* __restrict__ mean_index,
    int4* __restrict__ idx4, int E, int NS, int NI, int NC, int M, int nZero4)
{
    __shared__ u16 wlds[128 * WLDS_STRIDE];

    const int PB0 = (NS + 63) / 64, PB1 = (NI + 63) / 64, PB2 = (NC + 63) / 64;
    const int PBtot = PB0 + PB1 + 2 * PB2;
    const int ROLES = PACK_BLOCKS + PBtot;

    // ---------------- Phase A: pack/zero + projections ----------------
    for (int role = blockIdx.x; role < ROLES; role += gridDim.x) {
        if (role < PACK_BLOCKS) {
            const int tid0 = role * 256 + threadIdx.x;
            const int stride = PACK_BLOCKS * 256;
            const float4 z = {0.f, 0.f, 0.f, 0.f};
            for (int i = tid0; i < nZero4; i += stride) ((float4*)sc)[i] = z;
            for (int e = tid0; e < E; e += stride) {
                int4 t;
                t.x = stu_track[e]  << 8;   // 256 B rows
                t.y = item_index[e] << 8;   // 256 B rows
                t.z = conc_index[e] << 9;   // 512 B rows (cat)
                t.w = mean_index[e] << 3;   // f64 slots
                idx4[e] = t;
            }
        } else {
            __syncthreads();   // wlds from previous role iteration fully read
            proj_role(role - PACK_BLOCKS, wlds,
                      stu_x, item_x, conc_x, Wstu, Witem, b_stu, b_item,
                      stu_p, item_p, conc_cat, NS, NI, NC, PB0, PB1, PB2);
        }
    }

    __threadfence();                       // device-scope: cross-XCD visibility
    cooperative_groups::this_grid().sync();

    // ---------------- Phase B: edge (R8 proven structure) ----------------
    {
        const int lane = threadIdx.x & 63;
        const int sub  = lane & 15;      // position within edge
        const int g    = lane >> 4;      // edge within quad
        const int waveId = (int)((blockIdx.x * blockDim.x + threadIdx.x) >> 6);
        const int S      = (int)((gridDim.x * blockDim.x) >> 6);

        const float4 wA = ((const float4*)w_pred)[sub * 2];
        const float4 wB = ((const float4*)w_pred)[sub * 2 + 1];
        float2 w2[4];
        w2[0] = make_float2(wA.x, wA.y); w2[1] = make_float2(wA.z, wA.w);
        w2[2] = make_float2(wB.x, wB.y); w2[3] = make_float2(wB.z, wB.w);
        const u32 lane_off = (u32)sub * 16;

        const int nQuads = (E + 3) >> 2;
        int q = waveId;
        if (q < nQuads) {
            auto ldidx = [&](int qq) -> int4 {
                int e = qq * 4 + g;
                e = (e < E) ? e : (E - 1);
                return idx4[e];
            };
            auto compute = [&](const uint4& sv, const uint4& iv,
                               const uint4& ca, const uint4& cb,
                               u32 mw, int qq) {
                const u32 su[4] = {sv.x, sv.y, sv.z, sv.w};
                const u32 iu[4] = {iv.x, iv.y, iv.z, iv.w};
                const u32 au[4] = {ca.x, ca.y, ca.z, ca.w};
                const u32 bu[4] = {cb.x, cb.y, cb.z, cb.w};
                const float2 one = make_float2(1.f, 1.f);
                float2 vacc = make_float2(0.f, 0.f);
#pragma unroll
                for (int j = 0; j < 4; ++j) {
                    float2 A  = make_float2(bf2f_lo(au[j]), bf2f_hi(au[j]));
                    float2 Sx = make_float2(bf2f_lo(su[j]), bf2f_hi(su[j]));
                    float2 B  = make_float2(bf2f_lo(bu[j]), bf2f_hi(bu[j]));
                    float2 Ix = make_float2(bf2f_lo(iu[j]), bf2f_hi(iu[j]));
                    float2 ea = A * Sx;
                    float2 eb = B * Ix;
                    float2 den = (ea + one) * (eb + one);
                    float2 num = eb - ea;
                    float2 rd = make_float2(__builtin_amdgcn_rcpf(den.x),
                                            __builtin_amdgcn_rcpf(den.y));
                    vacc += (num * rd) * w2[j];
                }
                float v = vacc.x + vacc.y;
                v += __shfl_xor(v, 1, 64);
                v += __shfl_xor(v, 2, 64);
                v += __shfl_xor(v, 4, 64);
                v += __shfl_xor(v, 8, 64);
                if (sub == 0 && (qq * 4 + g) < E)
                    atomicAdd((double*)((char*)sc + mw), (double)v + CNT_SCALE);
            };

#define GATH_S(I_, sv_, iv_) { \
        sv_ = *(const uint4*)((const char*)stu_p  + ((u32)(I_).x + lane_off)); \
        iv_ = *(const uint4*)((const char*)item_p + ((u32)(I_).y + lane_off)); }
#define GATH_C(I_, ca_, cb_) { \
        const char* cp_ = (const char*)conc_cat + ((u32)(I_).z + lane_off); \
        ca_ = *(const uint4*)cp_; cb_ = *(const uint4*)(cp_ + 256); }
#define STEP(SC, CC, IC, ICN1, ICN2, SF, CF) { \
        const u32 mw = (u32)IC.w; \
        IC = ldidx(q + 3 * S); \
        __builtin_amdgcn_sched_barrier(0); \
        GATH_C(ICN1, CF##a, CF##b); \
        GATH_S(ICN2, SF##s, SF##i); \
        __builtin_amdgcn_sched_barrier(0); \
        compute(SC##s, SC##i, CC##a, CC##b, mw, q); \
        q += S; \
        if (q >= nQuads) break; }

            int4 i0 = ldidx(q), i1 = ldidx(q + S), i2 = ldidx(q + 2 * S);
            uint4 s0s, s0i, s1s, s1i, s2s, s2i, c0a, c0b, c1a, c1b;
            GATH_C(i0, c0a, c0b);
            GATH_S(i0, s0s, s0i);
            GATH_S(i1, s1s, s1i);

            for (;;) {
                STEP(s0, c0, i0, i1, i2, s2, c1)
                STEP(s1, c1, i1, i2, i0, s0, c0)
                STEP(s2, c0, i2, i0, i1, s1, c1)
                STEP(s0, c1, i0, i1, i2, s2, c0)
                STEP(s1, c0, i1, i2, i0, s0, c1)
                STEP(s2, c1, i2, i0, i1, s1, c0)
            }
#undef STEP
#undef GATH_S
#undef GATH_C
        }
    }

    __threadfence();
    cooperative_groups::this_grid().sync();

    // ---------------- Phase C: final ----------------
    for (int i = blockIdx.x * 256 + threadIdx.x; i < M; i += gridDim.x * 256) {
        const double acc = sc[i];
        const double cnt = rint(acc * (1.0 / CNT_SCALE));
        const double sum = acc - cnt * CNT_SCALE;
        const float mean = (float)(sum / fmax(cnt, 1.0));
        out[i] = sig_std(mean + b_pred[0]);
    }
}

// ===================== FALLBACK: proven R13 3-kernel path ====================
__global__ __launch_bounds__(256) void fused_prep_proj(
    const float* __restrict__ stu_x, const float* __restrict__ item_x,
    const float* __restrict__ conc_x,
    const float* __restrict__ Wstu, const float* __restrict__ Witem,
    const float* __restrict__ b_stu, const float* __restrict__ b_item,
    u16* __restrict__ stu_p, u16* __restrict__ item_p, u16* __restrict__ conc_cat,
    float4* __restrict__ zero4, int nZero4,
    const int* __restrict__ stu_track, const int* __restrict__ item_index,
    const int* __restrict__ conc_index, const int* __restrict__ mean_index,
    int4* __restrict__ idx4, int E,
    int NS, int NI, int NC)
{
    __shared__ u16 wlds[128 * WLDS_STRIDE];
    const int PB0 = (NS + 63) / 64, PB1 = (NI + 63) / 64, PB2 = (NC + 63) / 64;
    const int PBtot = PB0 + PB1 + 2 * PB2;
    int b = blockIdx.x;
    if (b < PACK_BLOCKS) {
        const int tid = b * 256 + threadIdx.x;
        const int stride = PACK_BLOCKS * 256;
        const float4 z = {0.f, 0.f, 0.f, 0.f};
        for (int i = tid; i < nZero4; i += stride) zero4[i] = z;
        for (int e = tid; e < E; e += stride) {
            int4 t;
            t.x = stu_track[e]  << 8;
            t.y = item_index[e] << 8;
            t.z = conc_index[e] << 9;
            t.w = mean_index[e] << 3;
            idx4[e] = t;
        }
        return;
    }
    b -= PACK_BLOCKS;
    if (b >= PBtot) return;
    proj_role(b, wlds, stu_x, item_x, conc_x, Wstu, Witem, b_stu, b_item,
              stu_p, item_p, conc_cat, NS, NI, NC, PB0, PB1, PB2);
}

__global__ __launch_bounds__(256) void edge_kernel(
    const u16* __restrict__ stu_p, const u16* __restrict__ item_p,
    const u16* __restrict__ conc_cat,
    const int4* __restrict__ idx4,
    const float* __restrict__ w_pred,
    double* __restrict__ sc, int E)
{
    const int lane = threadIdx.x & 63;
    const int sub  = lane & 15;
    const int g    = lane >> 4;
    const int waveId = (int)((blockIdx.x * blockDim.x + threadIdx.x) >> 6);
    const int S      = (int)((gridDim.x * blockDim.x) >> 6);

    const float4 wA = ((const float4*)w_pred)[sub * 2];
    const float4 wB = ((const float4*)w_pred)[sub * 2 + 1];
    float2 w2[4];
    w2[0] = make_float2(wA.x, wA.y); w2[1] = make_float2(wA.z, wA.w);
    w2[2] = make_float2(wB.x, wB.y); w2[3] = make_float2(wB.z, wB.w);
    const u32 lane_off = (u32)sub * 16;

    const int nQuads = (E + 3) >> 2;
    int q = waveId;
    if (q >= nQuads) return;

    auto ldidx = [&](int qq) -> int4 {
        int e = qq * 4 + g;
        e = (e < E) ? e : (E - 1);
        return idx4[e];
    };
    auto compute = [&](const uint4& sv, const uint4& iv,
                       const uint4& ca, const uint4& cb,
                       u32 mw, int qq) {
        const u32 su[4] = {sv.x, sv.y, sv.z, sv.w};
        const u32 iu[4] = {iv.x, iv.y, iv.z, iv.w};
        const u32 au[4] = {ca.x, ca.y, ca.z, ca.w};
        const u32 bu[4] = {cb.x, cb.y, cb.z, cb.w};
        const float2 one = make_float2(1.f, 1.f);
        float2 vacc = make_float2(0.f, 0.f);
#pragma unroll
        for (int j = 0; j < 4; ++j) {
            float2 A  = make_float2(bf2f_lo(au[j]), bf2f_hi(au[j]));
            float2 Sx = make_float2(bf2f_lo(su[j]), bf2f_hi(su[j]));
            float2 B  = make_float2(bf2f_lo(bu[j]), bf2f_hi(bu[j]));
            float2 Ix = make_float2(bf2f_lo(iu[j]), bf2f_hi(iu[j]));
            float2 ea = A * Sx;
            float2 eb = B * Ix;
            float2 den = (ea + one) * (eb + one);
            float2 num = eb - ea;
            float2 rd = make_float2(__builtin_amdgcn_rcpf(den.x),
                                    __builtin_amdgcn_rcpf(den.y));
            vacc += (num * rd) * w2[j];
        }
        float v = vacc.x + vacc.y;
        v += __shfl_xor(v, 1, 64);
        v += __shfl_xor(v, 2, 64);
        v += __shfl_xor(v, 4, 64);
        v += __shfl_xor(v, 8, 64);
        if (sub == 0 && (qq * 4 + g) < E)
            atomicAdd((double*)((char*)sc + mw), (double)v + CNT_SCALE);
    };

#define GATH_S(I_, sv_, iv_) { \
        sv_ = *(const uint4*)((const char*)stu_p  + ((u32)(I_).x + lane_off)); \
        iv_ = *(const uint4*)((const char*)item_p + ((u32)(I_).y + lane_off)); }
#define GATH_C(I_, ca_, cb_) { \
        const char* cp_ = (const char*)conc_cat + ((u32)(I_).z + lane_off); \
        ca_ = *(const uint4*)cp_; cb_ = *(const uint4*)(cp_ + 256); }
#define STEP(SC, CC, IC, ICN1, ICN2, SF, CF) { \
        const u32 mw = (u32)IC.w; \
        IC = ldidx(q + 3 * S); \
        __builtin_amdgcn_sched_barrier(0); \
        GATH_C(ICN1, CF##a, CF##b); \
        GATH_S(ICN2, SF##s, SF##i); \
        __builtin_amdgcn_sched_barrier(0); \
        compute(SC##s, SC##i, CC##a, CC##b, mw, q); \
        q += S; \
        if (q >= nQuads) break; }

    int4 i0 = ldidx(q), i1 = ldidx(q + S), i2 = ldidx(q + 2 * S);
    uint4 s0s, s0i, s1s, s1i, s2s, s2i, c0a, c0b, c1a, c1b;
    GATH_C(i0, c0a, c0b);
    GATH_S(i0, s0s, s0i);
    GATH_S(i1, s1s, s1i);

    for (;;) {
        STEP(s0, c0, i0, i1, i2, s2, c1)
        STEP(s1, c1, i1, i2, i0, s0, c0)
        STEP(s2, c0, i2, i0, i1, s1, c1)
        STEP(s0, c1, i0, i1, i2, s2, c0)
        STEP(s1, c0, i1, i2, i0, s0, c1)
        STEP(s2, c1, i2, i0, i1, s1, c0)
    }
#undef STEP
#undef GATH_S
#undef GATH_C
}

__global__ __launch_bounds__(256) void final_kernel(
    const double* __restrict__ sc,
    const float* __restrict__ b_pred, float* __restrict__ out, int M)
{
    const int i = blockIdx.x * blockDim.x + threadIdx.x;
    if (i < M) {
        const double acc = sc[i];
        const double cnt = rint(acc * (1.0 / CNT_SCALE));
        const double sum = acc - cnt * CNT_SCALE;
        const float mean = (float)(sum / fmax(cnt, 1.0));
        out[i] = sig_std(mean + b_pred[0]);
    }
}

extern "C" void kernel_launch(void* const* d_in, const int* in_sizes, int n_in,
                              void* d_out, int out_size, void* d_ws, size_t ws_size,
                              hipStream_t stream) {
    const float* stu_x    = (const float*)d_in[0];
    const float* item_x   = (const float*)d_in[1];
    const float* conc_x   = (const float*)d_in[2];
    const float* W_stu    = (const float*)d_in[3];
    const float* b_stu    = (const float*)d_in[4];
    const float* W_item   = (const float*)d_in[5];
    const float* b_item   = (const float*)d_in[6];
    const float* W_pred   = (const float*)d_in[7];
    const float* b_pred   = (const float*)d_in[8];
    const int* stu_track  = (const int*)d_in[9];
    const int* item_index = (const int*)d_in[10];
    const int* conc_index = (const int*)d_in[11];
    const int* mean_index = (const int*)d_in[12];

    int NS = in_sizes[0] / CDIM;
    int NI = in_sizes[1] / CDIM;
    int NC = in_sizes[2] / CDIM;
    int E  = in_sizes[9];
    int M  = out_size;

    // workspace layout (all pieces 16B-aligned)
    double* sc     = (double*)d_ws;              // [M] packed (sum + cnt*2^24)
    u16* stu_p     = (u16*)(sc + M);
    u16* item_p    = stu_p  + (size_t)NS * CDIM;
    u16* conc_cat  = item_p + (size_t)NI * CDIM; // [NC][256]: exp2 stu | item side
    int4* idx4     = (int4*)(conc_cat + (size_t)NC * 256);

    int nZero4 = (int)(((size_t)M * sizeof(double)) / 16);
    const int PB0 = (NS + 63) / 64, PB1 = (NI + 63) / 64, PB2 = (NC + 63) / 64;
    const int PBtot = PB0 + PB1 + 2 * PB2;

    // ---- try single cooperative launch ----
    int dev = 0;
    (void)hipGetDevice(&dev);
    int coop = 0, numCU = 0, bpc = 0;
    (void)hipDeviceGetAttribute(&coop, hipDeviceAttributeCooperativeLaunch, dev);
    (void)hipDeviceGetAttribute(&numCU, hipDeviceAttributeMultiprocessorCount, dev);
    (void)hipOccupancyMaxActiveBlocksPerMultiprocessor(&bpc, mega_kernel, 256, 0);
    long long Gll = (long long)bpc * (long long)numCU;
    int G = (Gll > 2048) ? 2048 : (int)Gll;

    if (coop && G >= 256) {
        float* outp = (float*)d_out;
        void* args[] = {
            (void*)&stu_x, (void*)&item_x, (void*)&conc_x,
            (void*)&W_stu, (void*)&W_item,
            (void*)&b_stu, (void*)&b_item,
            (void*)&W_pred, (void*)&b_pred,
            (void*)&stu_p, (void*)&item_p, (void*)&conc_cat,
            (void*)&sc, (void*)&outp,
            (void*)&stu_track, (void*)&item_index,
            (void*)&conc_index, (void*)&mean_index,
            (void*)&idx4, (void*)&E, (void*)&NS, (void*)&NI, (void*)&NC,
            (void*)&M, (void*)&nZero4
        };
        hipError_t err = hipLaunchCooperativeKernel(
            (const void*)mega_kernel, dim3(G), dim3(256), args, 0, stream);
        if (err == hipSuccess) return;
    }

    // ---- fallback: proven R13 3-kernel path (190.4 us) ----
    fused_prep_proj<<<PACK_BLOCKS + PBtot, 256, 0, stream>>>(
        stu_x, item_x, conc_x, W_stu, W_item, b_stu, b_item,
        stu_p, item_p, conc_cat,
        (float4*)sc, nZero4,
        stu_track, item_index, conc_index, mean_index, idx4, E,
        NS, NI, NC);
    edge_kernel<<<4096, 256, 0, stream>>>(stu_p, item_p, conc_cat,
                                          idx4, W_pred, sc, E);
    final_kernel<<<(M + 255) / 256, 256, 0, stream>>>(sc, b_pred, (float*)d_out, M);
}

// Round 16
// 192.218 us; speedup vs baseline: 5.3837x; 2.4139x over previous
//
#include <hip/hip_runtime.h>

typedef unsigned short u16;
typedef unsigned int   u32;

typedef short short8 __attribute__((ext_vector_type(8)));
typedef float floatx4 __attribute__((ext_vector_type(4)));

#define CDIM 128
#define K_NEG_LOG2E -1.4426950408889634f
#define CNT_SCALE 16777216.0   // 2^24: packs (sum, count) into one f64

// LDS weight tile: 128 rows x 136 u16 (272 B stride = 17*16 B).
#define WLDS_STRIDE 136
#define PACK_BLOCKS 512

__device__ __forceinline__ float bf2f_lo(u32 h) {
    union { u32 u; float f; } v; v.u = h << 16; return v.f;
}
__device__ __forceinline__ float bf2f_hi(u32 h) {
    union { u32 u; float f; } v; v.u = h & 0xffff0000u; return v.f;
}
__device__ __forceinline__ u16 f2bf(float f) {
    union { float f; u32 u; } v; v.f = f;
    u32 u = v.u;
    return (u16)((u + 0x7FFFu + ((u >> 16) & 1u)) >> 16);  // RNE
}
__device__ __forceinline__ float sig_std(float x) {
    return __builtin_amdgcn_rcpf(1.0f + __builtin_amdgcn_exp2f(x * K_NEG_LOG2E));
}

// One wave computes a 16-row tile from the LDS weight tile; stores
// exp2(proj + bias) in bf16.
__device__ __forceinline__ void proj_tile16_lds(
    const float* __restrict__ X, const u16* __restrict__ wlds,
    const float* __restrict__ bias, u16* __restrict__ out,
    int nrows, int ostride, int ooff, int row0, int lane)
{
    const int m = lane & 15;   // A-row / B-col / D-col
    const int g = lane >> 4;   // k-quad

    short8 a[4];
    {
        int arow = row0 + m;
        if (arow >= nrows) arow = nrows - 1;   // clamp; stores masked below
        const float* xrow = X + (size_t)arow * CDIM;
#pragma unroll
        for (int s = 0; s < 4; ++s) {
            float4 f0 = *(const float4*)(xrow + s * 32 + g * 8);
            float4 f1 = *(const float4*)(xrow + s * 32 + g * 8 + 4);
            a[s][0] = (short)f2bf(f0.x); a[s][1] = (short)f2bf(f0.y);
            a[s][2] = (short)f2bf(f0.z); a[s][3] = (short)f2bf(f0.w);
            a[s][4] = (short)f2bf(f1.x); a[s][5] = (short)f2bf(f1.y);
            a[s][6] = (short)f2bf(f1.z); a[s][7] = (short)f2bf(f1.w);
        }
    }

#pragma unroll
    for (int ct = 0; ct < 8; ++ct) {
        const u16* wrow = wlds + (size_t)(ct * 16 + m) * WLDS_STRIDE;
        floatx4 acc = {0.f, 0.f, 0.f, 0.f};
#pragma unroll
        for (int s = 0; s < 4; ++s) {
            short8 b = *(const short8*)(wrow + s * 32 + g * 8);
            acc = __builtin_amdgcn_mfma_f32_16x16x32_bf16(a[s], b, acc, 0, 0, 0);
        }
        const int col = ct * 16 + m;           // D: col = lane&15
        const float badd = bias ? bias[col] * K_NEG_LOG2E : 0.f;
#pragma unroll
        for (int i = 0; i < 4; ++i) {
            int r = row0 + g * 4 + i;          // D: row = (lane>>4)*4 + reg
            if (r < nrows)
                out[(size_t)r * ostride + ooff + col] =
                    f2bf(__builtin_amdgcn_exp2f(acc[i] + badd));
        }
    }
}

// ONE launch replacing prep+proj. Block roles (pack blocks FIRST):
//   [0, PACK_BLOCKS): zero f64 accumulators + pack edge indices (linear).
//   [PACK_BLOCKS, PACK_BLOCKS+PBtot): projection blocks.
__global__ __launch_bounds__(256) void fused_prep_proj(
    const float* __restrict__ stu_x, const float* __restrict__ item_x,
    const float* __restrict__ conc_x,
    const float* __restrict__ Wstu, const float* __restrict__ Witem,
    const float* __restrict__ b_stu, const float* __restrict__ b_item,
    u16* __restrict__ stu_p, u16* __restrict__ item_p, u16* __restrict__ conc_cat,
    float4* __restrict__ zero4, int nZero4,
    const int* __restrict__ stu_track, const int* __restrict__ item_index,
    const int* __restrict__ conc_index, const int* __restrict__ mean_index,
    int4* __restrict__ idx4, int E,
    int NS, int NI, int NC)
{
    __shared__ u16 wlds[128 * WLDS_STRIDE];

    const int PB0 = (NS + 63) / 64, PB1 = (NI + 63) / 64, PB2 = (NC + 63) / 64;
    const int PBtot = PB0 + PB1 + 2 * PB2;
    int b = blockIdx.x;

    if (b < PACK_BLOCKS) {
        // ---- pack/zero role ----
        const int tid = b * 256 + threadIdx.x;
        const int stride = PACK_BLOCKS * 256;
        const float4 z = {0.f, 0.f, 0.f, 0.f};
        for (int i = tid; i < nZero4; i += stride) zero4[i] = z;
        for (int e = tid; e < E; e += stride) {
            int4 t;
            t.x = stu_track[e]  << 8;   // 256 B rows
            t.y = item_index[e] << 8;   // 256 B rows
            t.z = conc_index[e] << 9;   // 512 B rows (cat)
            t.w = mean_index[e] << 3;   // f64 slots
            idx4[e] = t;
        }
        return;
    }
    b -= PACK_BLOCKS;
    if (b >= PBtot) return;

    // ---- projection role: segment select (block-uniform) ----
    const float* X; const float* Wsel; const float* bias;
    u16* out; int nrows, ostride, ooff, base;
    if (b < PB0)      { X = stu_x;  Wsel = Wstu;  bias = nullptr; out = stu_p;
                        nrows = NS; ostride = 128; ooff = 0;   base = b * 64; }
    else if ((b -= PB0) < PB1)
                      { X = item_x; Wsel = Witem; bias = nullptr; out = item_p;
                        nrows = NI; ostride = 128; ooff = 0;   base = b * 64; }
    else if ((b -= PB1) < PB2)
                      { X = conc_x; Wsel = Wstu;  bias = b_stu;  out = conc_cat;
                        nrows = NC; ostride = 256; ooff = 0;   base = b * 64; }
    else              { b -= PB2;
                        X = conc_x; Wsel = Witem; bias = b_item; out = conc_cat;
                        nrows = NC; ostride = 256; ooff = 128; base = b * 64; }

    // convert this block's W (f32 -> pre-scaled bf16) into LDS
    {
        const int t   = threadIdx.x;
        const int col = t >> 1;
        const int k0  = (t & 1) * 64;
        const float4* src = (const float4*)(Wsel + col * 128 + k0);
        u32* dst = (u32*)(wlds + col * WLDS_STRIDE + k0);
#pragma unroll
        for (int i = 0; i < 16; ++i) {
            float4 f = src[i];
            dst[2 * i]     = (u32)f2bf(f.x * K_NEG_LOG2E) |
                             ((u32)f2bf(f.y * K_NEG_LOG2E) << 16);
            dst[2 * i + 1] = (u32)f2bf(f.z * K_NEG_LOG2E) |
                             ((u32)f2bf(f.w * K_NEG_LOG2E) << 16);
        }
    }
    __syncthreads();

    const int lane = threadIdx.x & 63;
    const int row0 = base + (threadIdx.x >> 6) * 16;
    if (row0 < nrows)
        proj_tile16_lds(X, wlds, bias, out, nrows, ostride, ooff, row0, lane);
}

// 16 lanes per edge, 4 edges per wave. R8 session-best structure verbatim
// (edge 70.2-70.5 us, total 190.4 at R13): depth-2 stu/item, depth-1 conc,
// depth-3 idx issued FIRST each phase, 4096 blocks.
// Session findings (R0-R14), locked:
//  - MLP depth-2 at full grid: +5 us (R8 win)
//  - traffic cuts (conc->LDS, stu->XCD-L2 binning): FETCH -45%, time null
//  - DS->VALU reduce, VALU-trim: null/negative (not VALU-bound either)
//  - coop-launch fusion: grid.sync ~240 us each on this stack -> dead
//  => edge is latency/issue-BALANCED at ~70 us; all pipes < 60%.
__global__ __launch_bounds__(256) void edge_kernel(
    const u16* __restrict__ stu_p, const u16* __restrict__ item_p,
    const u16* __restrict__ conc_cat,
    const int4* __restrict__ idx4,     // byte offsets {stu, item, conc, mean}
    const float* __restrict__ w_pred,
    double* __restrict__ sc, int E)
{
    const int lane = threadIdx.x & 63;
    const int sub  = lane & 15;      // position within edge
    const int g    = lane >> 4;      // edge within quad
    const int waveId = (int)((blockIdx.x * blockDim.x + threadIdx.x) >> 6);
    const int S      = (int)((gridDim.x * blockDim.x) >> 6);   // wave stride

    const float4 wA = ((const float4*)w_pred)[sub * 2];
    const float4 wB = ((const float4*)w_pred)[sub * 2 + 1];
    float2 w2[4];
    w2[0] = make_float2(wA.x, wA.y); w2[1] = make_float2(wA.z, wA.w);
    w2[2] = make_float2(wB.x, wB.y); w2[3] = make_float2(wB.z, wB.w);
    const u32 lane_off = (u32)sub * 16;

    const int nQuads = (E + 3) >> 2;
    int q = waveId;
    if (q >= nQuads) return;

    // always-safe index load: edge id clamped to E-1
    auto ldidx = [&](int qq) -> int4 {
        int e = qq * 4 + g;
        e = (e < E) ? e : (E - 1);
        return idx4[e];
    };
    auto compute = [&](const uint4& sv, const uint4& iv,
                       const uint4& ca, const uint4& cb,
                       u32 mw, int qq) {
        const u32 su[4] = {sv.x, sv.y, sv.z, sv.w};
        const u32 iu[4] = {iv.x, iv.y, iv.z, iv.w};
        const u32 au[4] = {ca.x, ca.y, ca.z, ca.w};
        const u32 bu[4] = {cb.x, cb.y, cb.z, cb.w};
        const float2 one = make_float2(1.f, 1.f);
        float2 vacc = make_float2(0.f, 0.f);
#pragma unroll
        for (int j = 0; j < 4; ++j) {
            float2 A  = make_float2(bf2f_lo(au[j]), bf2f_hi(au[j]));
            float2 Sx = make_float2(bf2f_lo(su[j]), bf2f_hi(su[j]));
            float2 B  = make_float2(bf2f_lo(bu[j]), bf2f_hi(bu[j]));
            float2 Ix = make_float2(bf2f_lo(iu[j]), bf2f_hi(iu[j]));
            float2 ea = A * Sx;                    // v_pk_mul_f32
            float2 eb = B * Ix;
            float2 den = (ea + one) * (eb + one);  // (1+ea)(1+eb)
            float2 num = eb - ea;
            float2 rd = make_float2(__builtin_amdgcn_rcpf(den.x),
                                    __builtin_amdgcn_rcpf(den.y));
            vacc += (num * rd) * w2[j];
        }
        float v = vacc.x + vacc.y;
        v += __shfl_xor(v, 1, 64);
        v += __shfl_xor(v, 2, 64);
        v += __shfl_xor(v, 4, 64);
        v += __shfl_xor(v, 8, 64);
        if (sub == 0 && (qq * 4 + g) < E)
            atomicAdd((double*)((char*)sc + mw), (double)v + CNT_SCALE);
    };

#define GATH_S(I_, sv_, iv_) { \
        sv_ = *(const uint4*)((const char*)stu_p  + ((u32)(I_).x + lane_off)); \
        iv_ = *(const uint4*)((const char*)item_p + ((u32)(I_).y + lane_off)); }
#define GATH_C(I_, ca_, cb_) { \
        const char* cp_ = (const char*)conc_cat + ((u32)(I_).z + lane_off); \
        ca_ = *(const uint4*)cp_; cb_ = *(const uint4*)(cp_ + 256); }

    // Phase k: save mw, reload idx slot with I[k+3] (issued FIRST), gather
    // conc[k+1], gather stu/item[k+2], then compute S[k]/C[k]. The compiler's
    // FIFO vmcnt before compute leaves sv/iv[k+1], idx[k+3], conc[k+1],
    // sv/iv[k+2] in flight: 2 prefetch generations of table misses per wave.
#define STEP(SC, CC, IC, ICN1, ICN2, SF, CF) { \
        const u32 mw = (u32)IC.w; \
        IC = ldidx(q + 3 * S); \
        __builtin_amdgcn_sched_barrier(0); \
        GATH_C(ICN1, CF##a, CF##b); \
        GATH_S(ICN2, SF##s, SF##i); \
        __builtin_amdgcn_sched_barrier(0); \
        compute(SC##s, SC##i, CC##a, CC##b, mw, q); \
        q += S; \
        if (q >= nQuads) break; }

    // preamble: prime idx[0..2], conc[0], stu/item[0..1]
    int4 i0 = ldidx(q), i1 = ldidx(q + S), i2 = ldidx(q + 2 * S);
    uint4 s0s, s0i, s1s, s1i, s2s, s2i, c0a, c0b, c1a, c1b;
    GATH_C(i0, c0a, c0b);
    GATH_S(i0, s0s, s0i);
    GATH_S(i1, s1s, s1i);

    for (;;) {
        STEP(s0, c0, i0, i1, i2, s2, c1)   // k%6 == 0
        STEP(s1, c1, i1, i2, i0, s0, c0)   // k%6 == 1
        STEP(s2, c0, i2, i0, i1, s1, c1)   // k%6 == 2
        STEP(s0, c1, i0, i1, i2, s2, c0)   // k%6 == 3
        STEP(s1, c0, i1, i2, i0, s0, c1)   // k%6 == 4
        STEP(s2, c1, i2, i0, i1, s1, c0)   // k%6 == 5
    }
#undef STEP
#undef GATH_S
#undef GATH_C
}

__global__ __launch_bounds__(256) void final_kernel(
    const double* __restrict__ sc,
    const float* __restrict__ b_pred, float* __restrict__ out, int M)
{
    const int i = blockIdx.x * blockDim.x + threadIdx.x;
    if (i < M) {
        const double acc = sc[i];
        const double cnt = rint(acc * (1.0 / CNT_SCALE));   // |sum| << 2^23
        const double sum = acc - cnt * CNT_SCALE;
        const float mean = (float)(sum / fmax(cnt, 1.0));
        out[i] = sig_std(mean + b_pred[0]);
    }
}

extern "C" void kernel_launch(void* const* d_in, const int* in_sizes, int n_in,
                              void* d_out, int out_size, void* d_ws, size_t ws_size,
                              hipStream_t stream) {
    const float* stu_x    = (const float*)d_in[0];
    const float* item_x   = (const float*)d_in[1];
    const float* conc_x   = (const float*)d_in[2];
    const float* W_stu    = (const float*)d_in[3];
    const float* b_stu    = (const float*)d_in[4];
    const float* W_item   = (const float*)d_in[5];
    const float* b_item   = (const float*)d_in[6];
    const float* W_pred   = (const float*)d_in[7];
    const float* b_pred   = (const float*)d_in[8];
    const int* stu_track  = (const int*)d_in[9];
    const int* item_index = (const int*)d_in[10];
    const int* conc_index = (const int*)d_in[11];
    const int* mean_index = (const int*)d_in[12];

    const int NS = in_sizes[0] / CDIM;
    const int NI = in_sizes[1] / CDIM;
    const int NC = in_sizes[2] / CDIM;
    const int E  = in_sizes[9];
    const int M  = out_size;

    // workspace layout (all pieces 16B-aligned)
    double* sc     = (double*)d_ws;              // [M] packed (sum + cnt*2^24)
    u16* stu_p     = (u16*)(sc + M);
    u16* item_p    = stu_p  + (size_t)NS * CDIM;
    u16* conc_cat  = item_p + (size_t)NI * CDIM; // [NC][256]: exp2 stu | item side
    int4* idx4     = (int4*)(conc_cat + (size_t)NC * 256);

    const int nZero4 = (int)(((size_t)M * sizeof(double)) / 16);
    const int PB0 = (NS + 63) / 64, PB1 = (NI + 63) / 64, PB2 = (NC + 63) / 64;
    const int PBtot = PB0 + PB1 + 2 * PB2;

    fused_prep_proj<<<PACK_BLOCKS + PBtot, 256, 0, stream>>>(
        stu_x, item_x, conc_x, W_stu, W_item, b_stu, b_item,
        stu_p, item_p, conc_cat,
        (float4*)sc, nZero4,
        stu_track, item_index, conc_index, mean_index, idx4, E,
        NS, NI, NC);

    edge_kernel<<<4096, 256, 0, stream>>>(stu_p, item_p, conc_cat,
                                          idx4, W_pred, sc, E);

    final_kernel<<<(M + 255) / 256, 256, 0, stream>>>(sc, b_pred, (float*)d_out, M);
}